// Round 4
// baseline (653.108 us; speedup 1.0000x reference)
//
#include <hip/hip_runtime.h>

#define D_MODEL 1024
#define S_LEN   2048
#define BATCH   4
#define NH      16
#define DH      64
#define M_ROWS  (BATCH * S_LEN)   // 8192

typedef __attribute__((ext_vector_type(8))) short short8;
typedef __attribute__((ext_vector_type(4))) float floatx4;
typedef unsigned short ushort_t;
typedef __attribute__((ext_vector_type(4))) ushort_t ushortx4;

__device__ __forceinline__ ushort_t f2bf(float f) {
    union { float f; unsigned u; } v; v.f = f;
    unsigned r = v.u + 0x7FFFu + ((v.u >> 16) & 1u);
    return (ushort_t)(r >> 16);
}

// pack two f32 -> two bf16 (truncating) in one v_perm: low = lo, high = hi
__device__ __forceinline__ int pack2(float lo, float hi) {
    return (int)__builtin_amdgcn_perm(__float_as_uint(hi), __float_as_uint(lo), 0x07060302u);
}

// async global->LDS, 16B/lane; LDS dest = wave-uniform base + lane*16
__device__ __forceinline__ void async_copy16(const ushort_t* g, ushort_t* l) {
    __builtin_amdgcn_global_load_lds(
        (const __attribute__((address_space(1))) void*)g,
        (__attribute__((address_space(3))) void*)l,
        16, 0, 0);
}

// ---------------------------------------------------------------------------
// fp32 -> bf16 downcast of x, W_qkv, W_o into workspace. 4 elems / thread.
// ---------------------------------------------------------------------------
#define N0 (M_ROWS * D_MODEL)        // x:      8,388,608
#define N1 (3 * D_MODEL * D_MODEL)   // W_qkv:  3,145,728
#define N2 (D_MODEL * D_MODEL)       // W_o:    1,048,576
#define NQUADS ((N0 + N1 + N2) / 4)

__global__ __launch_bounds__(256)
void cvt_f32_bf16(const float* __restrict__ s0, const float* __restrict__ s1,
                  const float* __restrict__ s2, ushort_t* __restrict__ d0,
                  ushort_t* __restrict__ d1, ushort_t* __restrict__ d2)
{
    const int q = blockIdx.x * 256 + threadIdx.x;
    if (q >= NQUADS) return;
    const float* s; ushort_t* d; int e;
    if (q < N0 / 4)            { s = s0; d = d0; e = q * 4; }
    else if (q < (N0 + N1) / 4){ s = s1; d = d1; e = q * 4 - N0; }
    else                       { s = s2; d = d2; e = q * 4 - N0 - N1; }
    const float4 v = *(const float4*)&s[e];
    ushortx4 o;
    o[0] = f2bf(v.x); o[1] = f2bf(v.y); o[2] = f2bf(v.z); o[3] = f2bf(v.w);
    *(ushortx4*)&d[e] = o;
}

// ---------------------------------------------------------------------------
// NT GEMM: C[M,N] = A[M,K] * B[N,K]^T + bias[N]. bf16 in, fp32 acc.
// Tile BMxBN, BK=64, NWAVES waves (64x64 output per wave), SINGLE-buffered
// LDS with the proven two-barrier K-step (stage -> sync -> compute -> sync):
// cross-block wave overlap (>=2 resident blocks/CU) hides the DMA drain
// (m114 mechanism; 1-resident double-buffer measured WORSE in round 2).
// QKV: 256x128, 8 waves, 48 KB LDS -> 3 blocks/CU (launch_bounds caps VGPR).
// Oproj: 128x128, 4 waves, 32 KB LDS, grid 2/CU.
// XCD-aware bijective block swizzle: consecutive blocks on one XCD share the
// same A-panel -> A re-reads hit that XCD's L2 instead of HBM.
// XOR-swizzled unpadded LDS tiles: LDS(row,chunk) = global chunk^(row&7).
// VSPLIT (QKV): cols [0,2048) -> qk; cols [2048,3072) -> vt[b][h][dh][sperm],
// sperm = per-64-tile pos(k)=(k&15)*4+(k>>4) (matches attention fragments).
// Q columns (col < D_MODEL) pre-scaled by C2 = 0.125*log2(e) (exp2-domain).
// ---------------------------------------------------------------------------
template<int BM, int BN, int NWAVES, int MINW, bool F32OUT, bool VSPLIT>
__global__ __launch_bounds__(NWAVES * 64, MINW)
void gemm_bt_bias(const ushort_t* __restrict__ A, const ushort_t* __restrict__ B,
                  const float* __restrict__ bias, void* __restrict__ Cv,
                  ushort_t* __restrict__ vt, int M, int N, int K)
{
    constexpr int BK = 64;
    constexpr int AI = BM / 8 / NWAVES;   // A stage-issues per thread
    constexpr int BI = BN / 8 / NWAVES;   // B stage-issues per thread
    constexpr float C2 = 0.18033688011112042f;   // 0.125 * log2(e)
    __shared__ ushort_t As[BM][BK];
    __shared__ ushort_t Bs[BN][BK];

    const int tid  = threadIdx.x;
    const int lane = tid & 63;
    const int wave = tid >> 6;
    const int quad = lane >> 4;
    const int l16  = lane & 15;
    const int l8r  = lane >> 3;
    const int c8   = lane & 7;
    const int swz  = l16 & 7;

    // XCD-aware bijective swizzle (grid % 8 == 0 for both instantiations):
    // blocks dispatched round-robin to XCDs by original linear id; remap so
    // each XCD computes a contiguous chunk of tile space (x-fastest => chunk
    // shares A-panels).
    const int gdx = gridDim.x;
    const int bid = blockIdx.y * gdx + blockIdx.x;
    const int nwg = gdx * gridDim.y;
    const int sw  = (bid & 7) * (nwg >> 3) + (bid >> 3);
    const int bm  = (sw / gdx) * BM;
    const int bn  = (sw % gdx) * BN;

    const int wm = (wave % (BM / 64)) * 64;
    const int wn = (wave / (BM / 64)) * 64;

    // per-thread staging pointers (advance by BK each K-step)
    const ushort_t* ag[AI]; ushort_t* al[AI];
    const ushort_t* bg[BI]; ushort_t* bl[BI];
    #pragma unroll
    for (int i = 0; i < AI; i++) {
        const int ri = (wave + i * NWAVES) * 8;
        ag[i] = &A[(size_t)(bm + ri + l8r) * K + (c8 ^ l8r) * 8];
        al[i] = &As[ri][0];
    }
    #pragma unroll
    for (int i = 0; i < BI; i++) {
        const int ri = (wave + i * NWAVES) * 8;
        bg[i] = &B[(size_t)(bn + ri + l8r) * K + (c8 ^ l8r) * 8];
        bl[i] = &Bs[ri][0];
    }

    floatx4 acc[4][4] = {};

    for (int k0 = 0; k0 < K; k0 += BK) {
        __syncthreads();            // all waves done reading previous tile
        #pragma unroll
        for (int i = 0; i < AI; i++) async_copy16(ag[i] + k0, al[i]);
        #pragma unroll
        for (int i = 0; i < BI; i++) async_copy16(bg[i] + k0, bl[i]);
        __syncthreads();            // drains vmcnt(0): tile ready

        #pragma unroll
        for (int h = 0; h < 2; h++) {
            short8 af[4], bfr[4];
            #pragma unroll
            for (int i = 0; i < 4; i++)
                af[i]  = *(const short8*)&As[wm + i * 16 + l16][((h * 4 + quad) ^ swz) * 8];
            #pragma unroll
            for (int i = 0; i < 4; i++)
                bfr[i] = *(const short8*)&Bs[wn + i * 16 + l16][((h * 4 + quad) ^ swz) * 8];

            #pragma unroll
            for (int mi = 0; mi < 4; mi++)
                #pragma unroll
                for (int ni = 0; ni < 4; ni++)
                    acc[mi][ni] = __builtin_amdgcn_mfma_f32_16x16x32_bf16(af[mi], bfr[ni], acc[mi][ni], 0, 0, 0);
        }
    }

    #pragma unroll
    for (int ni = 0; ni < 4; ni++) {
        const int col = bn + wn + ni * 16 + l16;
        const float bv = bias[col];
        #pragma unroll
        for (int mi = 0; mi < 4; mi++)
            #pragma unroll
            for (int r = 0; r < 4; r++) {
                const int row = bm + wm + mi * 16 + quad * 4 + r;
                const float val = acc[mi][ni][r] + bv;
                if (VSPLIT) {
                    if (col < 2 * D_MODEL) {
                        // Q columns carry the softmax scale; K columns unscaled
                        const float vv = (col < D_MODEL) ? val * C2 : val;
                        ((ushort_t*)Cv)[(size_t)row * 2048 + col] = f2bf(vv);
                    } else {
                        const int vcol = col - 2 * D_MODEL;
                        const int h = vcol >> 6, dh = vcol & 63;
                        const int b = row >> 11, s = row & 2047;
                        const int sp = (s & ~63) | ((s & 15) << 2) | ((s >> 4) & 3);
                        vt[(((size_t)(b * NH + h)) * DH + dh) * S_LEN + sp] = f2bf(val);
                    }
                } else if (F32OUT) {
                    ((float*)Cv)[(size_t)row * N + col] = val;
                } else {
                    ((ushort_t*)Cv)[(size_t)row * N + col] = f2bf(val);
                }
            }
    }
}

// ---------------------------------------------------------------------------
// Causal flash attention: UNIFORM-WORK PAIRING, NO-MAX softmax, and
// DOUBLE-BUFFERED K/V staging (2-phase pipeline). (Unchanged — 4 blocks/CU.)
// ---------------------------------------------------------------------------
#define BKV 64

struct TileState {
    short8  qf[2];
    floatx4 o[4];
    float   l[4];
};

__device__ __forceinline__ void attn_tile(
    const ushort_t (*__restrict__ Ks)[DH], const ushort_t (*__restrict__ Vs)[BKV],
    ushort_t* __restrict__ Psw, TileState& st, bool diag,
    int wave, int quad, int l16, int swz, short8 ones)
{
    // ---- S = Q K^T (swizzled, conflict-free); Q pre-scaled by 0.125*log2e
    floatx4 sc[4];
    #pragma unroll
    for (int ns = 0; ns < 4; ns++) {
        const short8 kf0 = *(const short8*)&Ks[ns * 16 + l16][(quad ^ swz) * 8];
        const short8 kf1 = *(const short8*)&Ks[ns * 16 + l16][((4 + quad) ^ swz) * 8];
        floatx4 z = {};
        z = __builtin_amdgcn_mfma_f32_16x16x32_bf16(st.qf[0], kf0, z, 0, 0, 0);
        z = __builtin_amdgcn_mfma_f32_16x16x32_bf16(st.qf[1], kf1, z, 0, 0, 0);
        sc[ns] = z;
    }

    // ---- causal mask (diag only) + exp2 + pack + one b64 write per row
    #pragma unroll
    for (int r = 0; r < 4; r++) {
        const int qloc = wave * 16 + quad * 4 + r;   // row within the 64-row q-tile
        float p[4];
        #pragma unroll
        for (int ns = 0; ns < 4; ns++) {
            float v = sc[ns][r];
            if (diag) {
                const int kj = ns * 16 + l16;
                v = (kj <= qloc) ? v : -1e30f;
            }
            p[ns] = __builtin_amdgcn_exp2f(v);
        }
        int2 w;
        w.x = pack2(p[0], p[1]);
        w.y = pack2(p[2], p[3]);
        const int row = quad * 4 + r;
        // swizzled write: byte = row*128 + ((l16>>1)^(row&7))*16 + (l16&1)*8
        *(int2*)((char*)Psw + row * 128 + (((l16 >> 1) ^ (row & 7)) << 4) + ((l16 & 1) << 3)) = w;
    }

    // ---- P A-fragments (same-wave RAW through LDS, swizzled read)
    short8 pf[2];
    #pragma unroll
    for (int c = 0; c < 2; c++)
        pf[c] = *(const short8*)((const char*)Psw + l16 * 128 + ((((c << 2) | quad) ^ (l16 & 7)) << 4));

    // ---- row sums via MFMA (no rescale: accumulate directly)
    floatx4 racc = {};
    racc = __builtin_amdgcn_mfma_f32_16x16x32_bf16(pf[0], ones, racc, 0, 0, 0);
    racc = __builtin_amdgcn_mfma_f32_16x16x32_bf16(pf[1], ones, racc, 0, 0, 0);

    #pragma unroll
    for (int r = 0; r < 4; r++)
        st.l[r] += racc[r];

    // ---- O += P V (swizzled, position-permuted both sides)
    #pragma unroll
    for (int d = 0; d < 4; d++) {
        #pragma unroll
        for (int c = 0; c < 2; c++) {
            const short8 vf = *(const short8*)&Vs[d * 16 + l16][((c * 4 + quad) ^ swz) * 8];
            st.o[d] = __builtin_amdgcn_mfma_f32_16x16x32_bf16(pf[c], vf, st.o[d], 0, 0, 0);
        }
    }
}

__device__ __forceinline__ void stage_tile(
    const ushort_t* __restrict__ kg, const ushort_t* __restrict__ vg, int kb,
    ushort_t (*__restrict__ Ksb)[DH], ushort_t (*__restrict__ Vsb)[BKV],
    int wave, int l8r, int c8)
{
    #pragma unroll
    for (int i = wave; i < 8; i += 4) {
        const int row = i * 8 + l8r;
        const int cc  = (c8 ^ l8r) * 8;
        async_copy16(&kg[(size_t)(kb + row) * 2048 + cc], &Ksb[i * 8][0]);
        async_copy16(&vg[(size_t)row * S_LEN + kb + cc], &Vsb[i * 8][0]);
    }
}

__global__ __launch_bounds__(256, 4)
void attn_causal(const ushort_t* __restrict__ qk, const ushort_t* __restrict__ vt,
                 ushort_t* __restrict__ out)
{
    __shared__ ushort_t Ks[2][BKV][DH];       // double-buffered (16 KB)
    __shared__ ushort_t Vs[2][DH][BKV];       // double-buffered (16 KB)
    __shared__ ushort_t Ps[4][16][64];        // per-wave, XOR-swizzled (8 KB)
    // total 40960 B = 160 KB / 4 exactly

    const int tid  = threadIdx.x;
    const int lane = tid & 63;
    const int wave = tid >> 6;
    const int quad = lane >> 4;
    const int l16  = lane & 15;
    const int l8r  = lane >> 3;
    const int c8   = lane & 7;
    const int swz  = l16 & 7;

    const int qa = blockIdx.x;          // 0..15
    const int qb = 31 - qa;             // 16..31
    const int bh = blockIdx.y;
    const int b  = bh >> 4;
    const int h  = bh & 15;

    const size_t qkbase = (size_t)b * S_LEN * 2048;
    const ushort_t* kg = qk + qkbase + D_MODEL + h * DH;
    const ushort_t* vg = vt + (size_t)(b * NH + h) * DH * S_LEN;

    TileState sa, sb;
    #pragma unroll
    for (int r = 0; r < 4; r++) { sa.l[r] = 0.f; sb.l[r] = 0.f; }
    #pragma unroll
    for (int d = 0; d < 4; d++) { sa.o[d] = (floatx4){}; sb.o[d] = (floatx4){}; }

    {
        const ushort_t* qpa = qk + qkbase + (size_t)(qa * 64 + wave * 16 + l16) * 2048 + h * DH;
        sa.qf[0] = *(const short8*)(qpa + quad * 8);
        sa.qf[1] = *(const short8*)(qpa + 32 + quad * 8);
        const ushort_t* qpb = qk + qkbase + (size_t)(qb * 64 + wave * 16 + l16) * 2048 + h * DH;
        sb.qf[0] = *(const short8*)(qpb + quad * 8);
        sb.qf[1] = *(const short8*)(qpb + 32 + quad * 8);
    }

    short8 ones;
    #pragma unroll
    for (int j = 0; j < 8; j++) ones[j] = (short)0x3F80;   // bf16 1.0

    // prologue: stage tile 0 into buffer 0
    stage_tile(kg, vg, 0, Ks[0], Vs[0], wave, l8r, c8);

    int cur = 0;
    for (int t = 0; t <= qb; t++) {
        // Drains this wave's DMA (vmcnt(0)) then barriers: buf[cur] is ready
        // and all waves are done reading buf[cur^1] from iteration t-1.
        __syncthreads();
        if (t < qb)
            stage_tile(kg, vg, (t + 1) * BKV, Ks[cur ^ 1], Vs[cur ^ 1], wave, l8r, c8);

        if (t <= qa) attn_tile(Ks[cur], Vs[cur], &Ps[wave][0][0], sa, t == qa, wave, quad, l16, swz, ones);
        attn_tile(Ks[cur], Vs[cur], &Ps[wave][0][0], sb, t == qb, wave, quad, l16, swz, ones);
        cur ^= 1;
    }

    // ---- epilogue: out[b, qi, h*64 + dh] = o / l  (both tiles)
    #pragma unroll
    for (int r = 0; r < 4; r++) {
        const float inva = 1.0f / sa.l[r];
        const float invb = 1.0f / sb.l[r];
        const int ra = qa * 64 + wave * 16 + quad * 4 + r;
        const int rb = qb * 64 + wave * 16 + quad * 4 + r;
        #pragma unroll
        for (int d = 0; d < 4; d++) {
            out[(size_t)(b * S_LEN + ra) * D_MODEL + h * DH + d * 16 + l16] = f2bf(sa.o[d][r] * inva);
            out[(size_t)(b * S_LEN + rb) * D_MODEL + h * DH + d * 16 + l16] = f2bf(sb.o[d][r] * invb);
        }
    }
}

// ---------------------------------------------------------------------------
extern "C" void kernel_launch(void* const* d_in, const int* in_sizes, int n_in,
                              void* d_out, int out_size, void* d_ws, size_t ws_size,
                              hipStream_t stream)
{
    const float* x    = (const float*)d_in[0];
    const float* Wqkv = (const float*)d_in[1];
    const float* bqkv = (const float*)d_in[2];
    const float* Wo   = (const float*)d_in[3];
    const float* bo   = (const float*)d_in[4];
    float* out = (float*)d_out;

    ushort_t* xb    = (ushort_t*)d_ws;                       // N0
    ushort_t* wqkvb = xb + N0;                               // N1
    ushort_t* wob   = wqkvb + N1;                            // N2
    ushort_t* qkbuf = wob + N2;                              // 8192*2048
    ushort_t* vtbuf = qkbuf + (size_t)M_ROWS * 2048;         // B*NH*DH*S
    ushort_t* att   = vtbuf + (size_t)BATCH * NH * DH * S_LEN; // 8192*1024
    // total = 92.3 MB

    cvt_f32_bf16<<<dim3((NQUADS + 255) / 256), dim3(256), 0, stream>>>(x, Wqkv, Wo, xb, wqkvb, wob);
    // QKV projection: M=8192, N=3072, K=1024. 256x128 tile, 8 waves, 48 KB
    // LDS + VGPR<=85 -> 3 blocks/CU, grid 768 = 3/CU exact.
    gemm_bt_bias<256, 128, 8, 6, false, true>
        <<<dim3((3 * D_MODEL) / 128, M_ROWS / 256), dim3(512), 0, stream>>>(
        xb, wqkvb, bqkv, qkbuf, vtbuf, M_ROWS, 3 * D_MODEL, D_MODEL);
    // causal attention (paired q-tiles, no-max softmax, double-buffered K/V)
    attn_causal<<<dim3(16, BATCH * NH), dim3(256), 0, stream>>>(qkbuf, vtbuf, att);
    // output projection: M=8192, N=1024, K=1024. 128x128 tile, 4 waves,
    // 32 KB LDS, grid 512 = 2/CU.
    gemm_bt_bias<128, 128, 4, 2, true, false>
        <<<dim3(D_MODEL / 128, M_ROWS / 128), dim3(256), 0, stream>>>(
        att, wob, bo, out, nullptr, M_ROWS, D_MODEL, D_MODEL);
}

// Round 5
// 273.053 us; speedup vs baseline: 2.3919x; 2.3919x over previous
//
#include <hip/hip_runtime.h>

#define D_MODEL 1024
#define S_LEN   2048
#define BATCH   4
#define NH      16
#define DH      64
#define M_ROWS  (BATCH * S_LEN)   // 8192

typedef __attribute__((ext_vector_type(8))) short short8;
typedef __attribute__((ext_vector_type(4))) float floatx4;
typedef unsigned short ushort_t;
typedef __attribute__((ext_vector_type(4))) ushort_t ushortx4;

__device__ __forceinline__ ushort_t f2bf(float f) {
    union { float f; unsigned u; } v; v.f = f;
    unsigned r = v.u + 0x7FFFu + ((v.u >> 16) & 1u);
    return (ushort_t)(r >> 16);
}

// pack two f32 -> two bf16 (truncating) in one v_perm: low = lo, high = hi
__device__ __forceinline__ int pack2(float lo, float hi) {
    return (int)__builtin_amdgcn_perm(__float_as_uint(hi), __float_as_uint(lo), 0x07060302u);
}

// async global->LDS, 16B/lane; LDS dest = wave-uniform base + lane*16
__device__ __forceinline__ void async_copy16(const ushort_t* g, ushort_t* l) {
    __builtin_amdgcn_global_load_lds(
        (const __attribute__((address_space(1))) void*)g,
        (__attribute__((address_space(3))) void*)l,
        16, 0, 0);
}

// ---------------------------------------------------------------------------
// fp32 -> bf16 downcast of x, W_qkv, W_o into workspace. 4 elems / thread.
// ---------------------------------------------------------------------------
#define N0 (M_ROWS * D_MODEL)        // x:      8,388,608
#define N1 (3 * D_MODEL * D_MODEL)   // W_qkv:  3,145,728
#define N2 (D_MODEL * D_MODEL)       // W_o:    1,048,576
#define NQUADS ((N0 + N1 + N2) / 4)

__global__ __launch_bounds__(256)
void cvt_f32_bf16(const float* __restrict__ s0, const float* __restrict__ s1,
                  const float* __restrict__ s2, ushort_t* __restrict__ d0,
                  ushort_t* __restrict__ d1, ushort_t* __restrict__ d2)
{
    const int q = blockIdx.x * 256 + threadIdx.x;
    if (q >= NQUADS) return;
    const float* s; ushort_t* d; int e;
    if (q < N0 / 4)            { s = s0; d = d0; e = q * 4; }
    else if (q < (N0 + N1) / 4){ s = s1; d = d1; e = q * 4 - N0; }
    else                       { s = s2; d = d2; e = q * 4 - N0 - N1; }
    const float4 v = *(const float4*)&s[e];
    ushortx4 o;
    o[0] = f2bf(v.x); o[1] = f2bf(v.y); o[2] = f2bf(v.z); o[3] = f2bf(v.w);
    *(ushortx4*)&d[e] = o;
}

// ---------------------------------------------------------------------------
// NT GEMM: C[M,N] = A[M,K] * B[N,K]^T + bias[N]. bf16 in, fp32 acc.
// Tile BMxBN, BK=64, NWAVES waves (64x64 output per wave), SINGLE-buffered
// LDS with the proven two-barrier K-step (stage -> sync -> compute -> sync):
// cross-block wave overlap (>=2 resident blocks/CU) hides the DMA drain.
// QKV: 256x128, 8 waves, 48 KB LDS, launch_bounds(512,4): VGPR cap 128 >=
//   natural ~96 -> NO SPILL (round-3's MINW=6 capped at 85 and spilled acc
//   to scratch: VGPR=40, WRITE_SIZE=1.29GB, 4.4% MfmaUtil). ~2 blocks/CU.
// Oproj: 128x128, 4 waves, 32 KB LDS, grid 512 = 2/CU (256x128 would give a
//   256-block grid = 1/CU -> no cross-block overlap, the round-2 trap).
// XCD-aware bijective block swizzle: blocks with equal bid%8 land on one XCD
// and get contiguous tile-space chunks (x-fastest => shared A-panels in L2).
// XOR-swizzled unpadded LDS tiles: LDS(row,chunk) = global chunk^(row&7).
// VSPLIT (QKV): cols [0,2048) -> qk; cols [2048,3072) -> vt[b][h][dh][sperm],
// sperm = per-64-tile pos(k)=(k&15)*4+(k>>4) (matches attention fragments).
// Q columns (col < D_MODEL) pre-scaled by C2 = 0.125*log2(e) (exp2-domain).
// ---------------------------------------------------------------------------
template<int BM, int BN, int NWAVES, int MINW, bool F32OUT, bool VSPLIT>
__global__ __launch_bounds__(NWAVES * 64, MINW)
void gemm_bt_bias(const ushort_t* __restrict__ A, const ushort_t* __restrict__ B,
                  const float* __restrict__ bias, void* __restrict__ Cv,
                  ushort_t* __restrict__ vt, int M, int N, int K)
{
    constexpr int BK = 64;
    constexpr int AI = BM / 8 / NWAVES;   // A stage-issues per thread
    constexpr int BI = BN / 8 / NWAVES;   // B stage-issues per thread
    constexpr float C2 = 0.18033688011112042f;   // 0.125 * log2(e)
    __shared__ ushort_t As[BM][BK];
    __shared__ ushort_t Bs[BN][BK];

    const int tid  = threadIdx.x;
    const int lane = tid & 63;
    const int wave = tid >> 6;
    const int quad = lane >> 4;
    const int l16  = lane & 15;
    const int l8r  = lane >> 3;
    const int c8   = lane & 7;
    const int swz  = l16 & 7;

    // XCD-aware bijective swizzle (grid % 8 == 0 for both instantiations).
    const int gdx = gridDim.x;
    const int bid = blockIdx.y * gdx + blockIdx.x;
    const int nwg = gdx * gridDim.y;
    const int sw  = (bid & 7) * (nwg >> 3) + (bid >> 3);
    const int bm  = (sw / gdx) * BM;
    const int bn  = (sw % gdx) * BN;

    const int wm = (wave % (BM / 64)) * 64;
    const int wn = (wave / (BM / 64)) * 64;

    // per-thread staging pointers (advance by BK each K-step)
    const ushort_t* ag[AI]; ushort_t* al[AI];
    const ushort_t* bg[BI]; ushort_t* bl[BI];
    #pragma unroll
    for (int i = 0; i < AI; i++) {
        const int ri = (wave + i * NWAVES) * 8;
        ag[i] = &A[(size_t)(bm + ri + l8r) * K + (c8 ^ l8r) * 8];
        al[i] = &As[ri][0];
    }
    #pragma unroll
    for (int i = 0; i < BI; i++) {
        const int ri = (wave + i * NWAVES) * 8;
        bg[i] = &B[(size_t)(bn + ri + l8r) * K + (c8 ^ l8r) * 8];
        bl[i] = &Bs[ri][0];
    }

    floatx4 acc[4][4] = {};

    for (int k0 = 0; k0 < K; k0 += BK) {
        __syncthreads();            // all waves done reading previous tile
        #pragma unroll
        for (int i = 0; i < AI; i++) async_copy16(ag[i] + k0, al[i]);
        #pragma unroll
        for (int i = 0; i < BI; i++) async_copy16(bg[i] + k0, bl[i]);
        __syncthreads();            // drains vmcnt(0): tile ready

        #pragma unroll
        for (int h = 0; h < 2; h++) {
            short8 af[4], bfr[4];
            #pragma unroll
            for (int i = 0; i < 4; i++)
                af[i]  = *(const short8*)&As[wm + i * 16 + l16][((h * 4 + quad) ^ swz) * 8];
            #pragma unroll
            for (int i = 0; i < 4; i++)
                bfr[i] = *(const short8*)&Bs[wn + i * 16 + l16][((h * 4 + quad) ^ swz) * 8];

            #pragma unroll
            for (int mi = 0; mi < 4; mi++)
                #pragma unroll
                for (int ni = 0; ni < 4; ni++)
                    acc[mi][ni] = __builtin_amdgcn_mfma_f32_16x16x32_bf16(af[mi], bfr[ni], acc[mi][ni], 0, 0, 0);
        }
    }

    #pragma unroll
    for (int ni = 0; ni < 4; ni++) {
        const int col = bn + wn + ni * 16 + l16;
        const float bv = bias[col];
        #pragma unroll
        for (int mi = 0; mi < 4; mi++)
            #pragma unroll
            for (int r = 0; r < 4; r++) {
                const int row = bm + wm + mi * 16 + quad * 4 + r;
                const float val = acc[mi][ni][r] + bv;
                if (VSPLIT) {
                    if (col < 2 * D_MODEL) {
                        // Q columns carry the softmax scale; K columns unscaled
                        const float vv = (col < D_MODEL) ? val * C2 : val;
                        ((ushort_t*)Cv)[(size_t)row * 2048 + col] = f2bf(vv);
                    } else {
                        const int vcol = col - 2 * D_MODEL;
                        const int h = vcol >> 6, dh = vcol & 63;
                        const int b = row >> 11, s = row & 2047;
                        const int sp = (s & ~63) | ((s & 15) << 2) | ((s >> 4) & 3);
                        vt[(((size_t)(b * NH + h)) * DH + dh) * S_LEN + sp] = f2bf(val);
                    }
                } else if (F32OUT) {
                    ((float*)Cv)[(size_t)row * N + col] = val;
                } else {
                    ((ushort_t*)Cv)[(size_t)row * N + col] = f2bf(val);
                }
            }
    }
}

// ---------------------------------------------------------------------------
// Causal flash attention: UNIFORM-WORK PAIRING, NO-MAX softmax, and
// DOUBLE-BUFFERED K/V staging (2-phase pipeline). (Unchanged — 4 blocks/CU.)
// ---------------------------------------------------------------------------
#define BKV 64

struct TileState {
    short8  qf[2];
    floatx4 o[4];
    float   l[4];
};

__device__ __forceinline__ void attn_tile(
    const ushort_t (*__restrict__ Ks)[DH], const ushort_t (*__restrict__ Vs)[BKV],
    ushort_t* __restrict__ Psw, TileState& st, bool diag,
    int wave, int quad, int l16, int swz, short8 ones)
{
    // ---- S = Q K^T (swizzled, conflict-free); Q pre-scaled by 0.125*log2e
    floatx4 sc[4];
    #pragma unroll
    for (int ns = 0; ns < 4; ns++) {
        const short8 kf0 = *(const short8*)&Ks[ns * 16 + l16][(quad ^ swz) * 8];
        const short8 kf1 = *(const short8*)&Ks[ns * 16 + l16][((4 + quad) ^ swz) * 8];
        floatx4 z = {};
        z = __builtin_amdgcn_mfma_f32_16x16x32_bf16(st.qf[0], kf0, z, 0, 0, 0);
        z = __builtin_amdgcn_mfma_f32_16x16x32_bf16(st.qf[1], kf1, z, 0, 0, 0);
        sc[ns] = z;
    }

    // ---- causal mask (diag only) + exp2 + pack + one b64 write per row
    #pragma unroll
    for (int r = 0; r < 4; r++) {
        const int qloc = wave * 16 + quad * 4 + r;   // row within the 64-row q-tile
        float p[4];
        #pragma unroll
        for (int ns = 0; ns < 4; ns++) {
            float v = sc[ns][r];
            if (diag) {
                const int kj = ns * 16 + l16;
                v = (kj <= qloc) ? v : -1e30f;
            }
            p[ns] = __builtin_amdgcn_exp2f(v);
        }
        int2 w;
        w.x = pack2(p[0], p[1]);
        w.y = pack2(p[2], p[3]);
        const int row = quad * 4 + r;
        // swizzled write: byte = row*128 + ((l16>>1)^(row&7))*16 + (l16&1)*8
        *(int2*)((char*)Psw + row * 128 + (((l16 >> 1) ^ (row & 7)) << 4) + ((l16 & 1) << 3)) = w;
    }

    // ---- P A-fragments (same-wave RAW through LDS, swizzled read)
    short8 pf[2];
    #pragma unroll
    for (int c = 0; c < 2; c++)
        pf[c] = *(const short8*)((const char*)Psw + l16 * 128 + ((((c << 2) | quad) ^ (l16 & 7)) << 4));

    // ---- row sums via MFMA (no rescale: accumulate directly)
    floatx4 racc = {};
    racc = __builtin_amdgcn_mfma_f32_16x16x32_bf16(pf[0], ones, racc, 0, 0, 0);
    racc = __builtin_amdgcn_mfma_f32_16x16x32_bf16(pf[1], ones, racc, 0, 0, 0);

    #pragma unroll
    for (int r = 0; r < 4; r++)
        st.l[r] += racc[r];

    // ---- O += P V (swizzled, position-permuted both sides)
    #pragma unroll
    for (int d = 0; d < 4; d++) {
        #pragma unroll
        for (int c = 0; c < 2; c++) {
            const short8 vf = *(const short8*)&Vs[d * 16 + l16][((c * 4 + quad) ^ swz) * 8];
            st.o[d] = __builtin_amdgcn_mfma_f32_16x16x32_bf16(pf[c], vf, st.o[d], 0, 0, 0);
        }
    }
}

__device__ __forceinline__ void stage_tile(
    const ushort_t* __restrict__ kg, const ushort_t* __restrict__ vg, int kb,
    ushort_t (*__restrict__ Ksb)[DH], ushort_t (*__restrict__ Vsb)[BKV],
    int wave, int l8r, int c8)
{
    #pragma unroll
    for (int i = wave; i < 8; i += 4) {
        const int row = i * 8 + l8r;
        const int cc  = (c8 ^ l8r) * 8;
        async_copy16(&kg[(size_t)(kb + row) * 2048 + cc], &Ksb[i * 8][0]);
        async_copy16(&vg[(size_t)row * S_LEN + kb + cc], &Vsb[i * 8][0]);
    }
}

__global__ __launch_bounds__(256, 4)
void attn_causal(const ushort_t* __restrict__ qk, const ushort_t* __restrict__ vt,
                 ushort_t* __restrict__ out)
{
    __shared__ ushort_t Ks[2][BKV][DH];       // double-buffered (16 KB)
    __shared__ ushort_t Vs[2][DH][BKV];       // double-buffered (16 KB)
    __shared__ ushort_t Ps[4][16][64];        // per-wave, XOR-swizzled (8 KB)
    // total 40960 B = 160 KB / 4 exactly

    const int tid  = threadIdx.x;
    const int lane = tid & 63;
    const int wave = tid >> 6;
    const int quad = lane >> 4;
    const int l16  = lane & 15;
    const int l8r  = lane >> 3;
    const int c8   = lane & 7;
    const int swz  = l16 & 7;

    const int qa = blockIdx.x;          // 0..15
    const int qb = 31 - qa;             // 16..31
    const int bh = blockIdx.y;
    const int b  = bh >> 4;
    const int h  = bh & 15;

    const size_t qkbase = (size_t)b * S_LEN * 2048;
    const ushort_t* kg = qk + qkbase + D_MODEL + h * DH;
    const ushort_t* vg = vt + (size_t)(b * NH + h) * DH * S_LEN;

    TileState sa, sb;
    #pragma unroll
    for (int r = 0; r < 4; r++) { sa.l[r] = 0.f; sb.l[r] = 0.f; }
    #pragma unroll
    for (int d = 0; d < 4; d++) { sa.o[d] = (floatx4){}; sb.o[d] = (floatx4){}; }

    {
        const ushort_t* qpa = qk + qkbase + (size_t)(qa * 64 + wave * 16 + l16) * 2048 + h * DH;
        sa.qf[0] = *(const short8*)(qpa + quad * 8);
        sa.qf[1] = *(const short8*)(qpa + 32 + quad * 8);
        const ushort_t* qpb = qk + qkbase + (size_t)(qb * 64 + wave * 16 + l16) * 2048 + h * DH;
        sb.qf[0] = *(const short8*)(qpb + quad * 8);
        sb.qf[1] = *(const short8*)(qpb + 32 + quad * 8);
    }

    short8 ones;
    #pragma unroll
    for (int j = 0; j < 8; j++) ones[j] = (short)0x3F80;   // bf16 1.0

    // prologue: stage tile 0 into buffer 0
    stage_tile(kg, vg, 0, Ks[0], Vs[0], wave, l8r, c8);

    int cur = 0;
    for (int t = 0; t <= qb; t++) {
        // Drains this wave's DMA (vmcnt(0)) then barriers: buf[cur] is ready
        // and all waves are done reading buf[cur^1] from iteration t-1.
        __syncthreads();
        if (t < qb)
            stage_tile(kg, vg, (t + 1) * BKV, Ks[cur ^ 1], Vs[cur ^ 1], wave, l8r, c8);

        if (t <= qa) attn_tile(Ks[cur], Vs[cur], &Ps[wave][0][0], sa, t == qa, wave, quad, l16, swz, ones);
        attn_tile(Ks[cur], Vs[cur], &Ps[wave][0][0], sb, t == qb, wave, quad, l16, swz, ones);
        cur ^= 1;
    }

    // ---- epilogue: out[b, qi, h*64 + dh] = o / l  (both tiles)
    #pragma unroll
    for (int r = 0; r < 4; r++) {
        const float inva = 1.0f / sa.l[r];
        const float invb = 1.0f / sb.l[r];
        const int ra = qa * 64 + wave * 16 + quad * 4 + r;
        const int rb = qb * 64 + wave * 16 + quad * 4 + r;
        #pragma unroll
        for (int d = 0; d < 4; d++) {
            out[(size_t)(b * S_LEN + ra) * D_MODEL + h * DH + d * 16 + l16] = f2bf(sa.o[d][r] * inva);
            out[(size_t)(b * S_LEN + rb) * D_MODEL + h * DH + d * 16 + l16] = f2bf(sb.o[d][r] * invb);
        }
    }
}

// ---------------------------------------------------------------------------
extern "C" void kernel_launch(void* const* d_in, const int* in_sizes, int n_in,
                              void* d_out, int out_size, void* d_ws, size_t ws_size,
                              hipStream_t stream)
{
    const float* x    = (const float*)d_in[0];
    const float* Wqkv = (const float*)d_in[1];
    const float* bqkv = (const float*)d_in[2];
    const float* Wo   = (const float*)d_in[3];
    const float* bo   = (const float*)d_in[4];
    float* out = (float*)d_out;

    ushort_t* xb    = (ushort_t*)d_ws;                       // N0
    ushort_t* wqkvb = xb + N0;                               // N1
    ushort_t* wob   = wqkvb + N1;                            // N2
    ushort_t* qkbuf = wob + N2;                              // 8192*2048
    ushort_t* vtbuf = qkbuf + (size_t)M_ROWS * 2048;         // B*NH*DH*S
    ushort_t* att   = vtbuf + (size_t)BATCH * NH * DH * S_LEN; // 8192*1024
    // total = 92.3 MB

    cvt_f32_bf16<<<dim3((NQUADS + 255) / 256), dim3(256), 0, stream>>>(x, Wqkv, Wo, xb, wqkvb, wob);
    // QKV projection: M=8192, N=3072, K=1024. 256x128 tile, 8 waves, 48 KB
    // LDS, launch_bounds(512,4) -> VGPR cap 128, no spill, ~2 blocks/CU.
    gemm_bt_bias<256, 128, 8, 4, false, true>
        <<<dim3((3 * D_MODEL) / 128, M_ROWS / 256), dim3(512), 0, stream>>>(
        xb, wqkvb, bqkv, qkbuf, vtbuf, M_ROWS, 3 * D_MODEL, D_MODEL);
    // causal attention (paired q-tiles, no-max softmax, double-buffered K/V)
    attn_causal<<<dim3(16, BATCH * NH), dim3(256), 0, stream>>>(qkbuf, vtbuf, att);
    // output projection: M=8192, N=1024, K=1024. 128x128 tile, 4 waves,
    // 32 KB LDS, grid 512 = 2/CU.
    gemm_bt_bias<128, 128, 4, 2, true, false>
        <<<dim3(D_MODEL / 128, M_ROWS / 128), dim3(256), 0, stream>>>(
        att, wob, bo, out, nullptr, M_ROWS, D_MODEL, D_MODEL);
}

// Round 6
// 269.228 us; speedup vs baseline: 2.4259x; 1.0142x over previous
//
#include <hip/hip_runtime.h>

#define D_MODEL 1024
#define S_LEN   2048
#define BATCH   4
#define NH      16
#define DH      64
#define M_ROWS  (BATCH * S_LEN)   // 8192

typedef __attribute__((ext_vector_type(8))) short short8;
typedef __attribute__((ext_vector_type(4))) float floatx4;
typedef unsigned short ushort_t;
typedef __attribute__((ext_vector_type(4))) ushort_t ushortx4;

__device__ __forceinline__ ushort_t f2bf(float f) {
    union { float f; unsigned u; } v; v.f = f;
    unsigned r = v.u + 0x7FFFu + ((v.u >> 16) & 1u);
    return (ushort_t)(r >> 16);
}

// pack two f32 -> two bf16 (truncating) in one v_perm: low = lo, high = hi
__device__ __forceinline__ int pack2(float lo, float hi) {
    return (int)__builtin_amdgcn_perm(__float_as_uint(hi), __float_as_uint(lo), 0x07060302u);
}

// async global->LDS, 16B/lane; LDS dest = wave-uniform base + lane*16
__device__ __forceinline__ void async_copy16(const ushort_t* g, ushort_t* l) {
    __builtin_amdgcn_global_load_lds(
        (const __attribute__((address_space(1))) void*)g,
        (__attribute__((address_space(3))) void*)l,
        16, 0, 0);
}

// ---------------------------------------------------------------------------
// fp32 -> bf16 downcast of x, W_qkv, W_o into workspace. 4 elems / thread.
// ---------------------------------------------------------------------------
#define N0 (M_ROWS * D_MODEL)        // x:      8,388,608
#define N1 (3 * D_MODEL * D_MODEL)   // W_qkv:  3,145,728
#define N2 (D_MODEL * D_MODEL)       // W_o:    1,048,576
#define NQUADS ((N0 + N1 + N2) / 4)

__global__ __launch_bounds__(256)
void cvt_f32_bf16(const float* __restrict__ s0, const float* __restrict__ s1,
                  const float* __restrict__ s2, ushort_t* __restrict__ d0,
                  ushort_t* __restrict__ d1, ushort_t* __restrict__ d2)
{
    const int q = blockIdx.x * 256 + threadIdx.x;
    if (q >= NQUADS) return;
    const float* s; ushort_t* d; int e;
    if (q < N0 / 4)            { s = s0; d = d0; e = q * 4; }
    else if (q < (N0 + N1) / 4){ s = s1; d = d1; e = q * 4 - N0; }
    else                       { s = s2; d = d2; e = q * 4 - N0 - N1; }
    const float4 v = *(const float4*)&s[e];
    ushortx4 o;
    o[0] = f2bf(v.x); o[1] = f2bf(v.y); o[2] = f2bf(v.z); o[3] = f2bf(v.w);
    *(ushortx4*)&d[e] = o;
}

// ---------------------------------------------------------------------------
// NT GEMM with COUNTED-VMCNT 3-SLOT PIPELINE.
// C[M,N] = A[M,K]*B[N,K]^T + bias[N]. bf16 in, fp32 acc. BM=256, BN=128,
// BK=64, 8 waves (4M x 2N, 64x64 per wave). LDS = 3 slots x 48 KB = 144 KB
// -> 1 block/CU, pipeline (not cross-block overlap) hides staging.
//
// Schedule per iteration t (ONE barrier, counted vmcnt — never 0 mid-loop):
//   s_waitcnt vmcnt(6)     // per-wave: exactly tile t+1's 6 loads remain
//                          // outstanding -> tile t's DMA complete
//   s_barrier              // all waves see tile t staged; all done reading
//                          // slot (t-1)%3 (program order before barrier)
//   STAGE(tile t+2 -> slot (t+2)%3)   // 6 global_load_lds per wave
//   compute tile t from slot t%3      // 16 ds_read_b128 + 32 MFMA per wave
// Slot invariant: write target (t+2)%3 != read slot t%3 != next (t+1)%3;
// previous occupant (t-1) fully consumed before this iter's barrier.
// Final iter waits vmcnt(0) (nothing left to prefetch).
// __syncthreads() is NOT used in the loop — its implicit vmcnt(0) drain is
// the ~550 TF ceiling of the 2-barrier structure (rounds 1-4).
//
// XOR-swizzled unpadded LDS tiles: LDS(row,chunk) = global chunk^(row&7).
// XCD-aware bijective block swizzle (shared A-panels within an XCD's L2).
// VSPLIT (QKV): cols [0,2048) -> qk; cols [2048,3072) -> vt[b][h][dh][sperm],
// sperm = per-64-tile pos(k)=(k&15)*4+(k>>4) (matches attention fragments).
// Q columns (col < D_MODEL) pre-scaled by C2 = 0.125*log2(e) (exp2-domain).
// ---------------------------------------------------------------------------
template<bool F32OUT, bool VSPLIT>
__global__ __launch_bounds__(512, 2)
void gemm_pipe(const ushort_t* __restrict__ A, const ushort_t* __restrict__ B,
               const float* __restrict__ bias, void* __restrict__ Cv,
               ushort_t* __restrict__ vt, int M, int N, int K)
{
    constexpr int BM = 256;
    constexpr int BN = 128;
    constexpr int BK = 64;
    constexpr float C2 = 0.18033688011112042f;   // 0.125 * log2(e)
    __shared__ ushort_t As[3][BM][BK];   // 96 KB
    __shared__ ushort_t Bs[3][BN][BK];   // 48 KB

    const int tid  = threadIdx.x;
    const int lane = tid & 63;
    const int wave = tid >> 6;           // 0..7
    const int quad = lane >> 4;
    const int l16  = lane & 15;
    const int l8r  = lane >> 3;
    const int c8   = lane & 7;
    const int swz  = l16 & 7;

    // XCD-aware bijective swizzle (grid % 8 == 0 for both instantiations).
    const int gdx = gridDim.x;
    const int bid = blockIdx.y * gdx + blockIdx.x;
    const int nwg = gdx * gridDim.y;
    const int sw  = (bid & 7) * (nwg >> 3) + (bid >> 3);
    const int bm  = (sw / gdx) * BM;
    const int bn  = (sw % gdx) * BN;

    const int wm = (wave & 3) * 64;      // 4 waves along M
    const int wn = (wave >> 2) * 64;     // 2 waves along N

    const int NT = K >> 6;               // 16 K-tiles

    // ---- stage tile kt into slot s: 6 global_load_lds per wave (4 A + 2 B)
    auto STAGE = [&](int s, int kt) {
        const int k0 = kt * BK;
        const int cc = (c8 ^ l8r) * 8;
        #pragma unroll
        for (int i = 0; i < 4; i++) {
            const int rb = (i * 8 + wave) * 8;
            async_copy16(&A[(size_t)(bm + rb + l8r) * K + k0 + cc], &As[s][rb][0]);
        }
        #pragma unroll
        for (int i = 0; i < 2; i++) {
            const int rb = (i * 8 + wave) * 8;
            async_copy16(&B[(size_t)(bn + rb + l8r) * K + k0 + cc], &Bs[s][rb][0]);
        }
    };

    // prologue: 2 tiles in flight (12 loads/wave outstanding)
    STAGE(0, 0);
    STAGE(1, 1);

    floatx4 acc[4][4] = {};

    for (int t = 0; t < NT; t++) {
        if (t + 1 < NT) {
            asm volatile("s_waitcnt vmcnt(6)" ::: "memory");   // tile t done, t+1 in flight
        } else {
            asm volatile("s_waitcnt vmcnt(0)" ::: "memory");   // last tile: full drain
        }
        __builtin_amdgcn_s_barrier();
        if (t + 2 < NT) STAGE((t + 2) % 3, t + 2);

        const int s = t % 3;
        #pragma unroll
        for (int h = 0; h < 2; h++) {
            short8 af[4], bfr[4];
            #pragma unroll
            for (int i = 0; i < 4; i++)
                af[i]  = *(const short8*)&As[s][wm + i * 16 + l16][((h * 4 + quad) ^ swz) * 8];
            #pragma unroll
            for (int i = 0; i < 4; i++)
                bfr[i] = *(const short8*)&Bs[s][wn + i * 16 + l16][((h * 4 + quad) ^ swz) * 8];

            #pragma unroll
            for (int mi = 0; mi < 4; mi++)
                #pragma unroll
                for (int ni = 0; ni < 4; ni++)
                    acc[mi][ni] = __builtin_amdgcn_mfma_f32_16x16x32_bf16(af[mi], bfr[ni], acc[mi][ni], 0, 0, 0);
        }
    }

    #pragma unroll
    for (int ni = 0; ni < 4; ni++) {
        const int col = bn + wn + ni * 16 + l16;
        const float bv = bias[col];
        #pragma unroll
        for (int mi = 0; mi < 4; mi++)
            #pragma unroll
            for (int r = 0; r < 4; r++) {
                const int row = bm + wm + mi * 16 + quad * 4 + r;
                const float val = acc[mi][ni][r] + bv;
                if (VSPLIT) {
                    if (col < 2 * D_MODEL) {
                        // Q columns carry the softmax scale; K columns unscaled
                        const float vv = (col < D_MODEL) ? val * C2 : val;
                        ((ushort_t*)Cv)[(size_t)row * 2048 + col] = f2bf(vv);
                    } else {
                        const int vcol = col - 2 * D_MODEL;
                        const int h = vcol >> 6, dh = vcol & 63;
                        const int b = row >> 11, s2 = row & 2047;
                        const int sp = (s2 & ~63) | ((s2 & 15) << 2) | ((s2 >> 4) & 3);
                        vt[(((size_t)(b * NH + h)) * DH + dh) * S_LEN + sp] = f2bf(val);
                    }
                } else if (F32OUT) {
                    ((float*)Cv)[(size_t)row * N + col] = val;
                } else {
                    ((ushort_t*)Cv)[(size_t)row * N + col] = f2bf(val);
                }
            }
    }
}

// ---------------------------------------------------------------------------
// Causal flash attention: UNIFORM-WORK PAIRING, NO-MAX softmax, DOUBLE-
// BUFFERED K/V staging. New this round: XCD-chunked (qa,bh) swizzle (8 bh per
// XCD -> K/V stays resident in that XCD's 4 MB L2) and s_setprio around the
// MFMA clusters (independent-block regime: m191-style +4-7%).
// ---------------------------------------------------------------------------
#define BKV 64

struct TileState {
    short8  qf[2];
    floatx4 o[4];
    float   l[4];
};

__device__ __forceinline__ void attn_tile(
    const ushort_t (*__restrict__ Ks)[DH], const ushort_t (*__restrict__ Vs)[BKV],
    ushort_t* __restrict__ Psw, TileState& st, bool diag,
    int wave, int quad, int l16, int swz, short8 ones)
{
    // ---- S = Q K^T (swizzled, conflict-free); Q pre-scaled by 0.125*log2e
    floatx4 sc[4];
    __builtin_amdgcn_s_setprio(1);
    #pragma unroll
    for (int ns = 0; ns < 4; ns++) {
        const short8 kf0 = *(const short8*)&Ks[ns * 16 + l16][(quad ^ swz) * 8];
        const short8 kf1 = *(const short8*)&Ks[ns * 16 + l16][((4 + quad) ^ swz) * 8];
        floatx4 z = {};
        z = __builtin_amdgcn_mfma_f32_16x16x32_bf16(st.qf[0], kf0, z, 0, 0, 0);
        z = __builtin_amdgcn_mfma_f32_16x16x32_bf16(st.qf[1], kf1, z, 0, 0, 0);
        sc[ns] = z;
    }
    __builtin_amdgcn_s_setprio(0);

    // ---- causal mask (diag only) + exp2 + pack + one b64 write per row
    #pragma unroll
    for (int r = 0; r < 4; r++) {
        const int qloc = wave * 16 + quad * 4 + r;   // row within the 64-row q-tile
        float p[4];
        #pragma unroll
        for (int ns = 0; ns < 4; ns++) {
            float v = sc[ns][r];
            if (diag) {
                const int kj = ns * 16 + l16;
                v = (kj <= qloc) ? v : -1e30f;
            }
            p[ns] = __builtin_amdgcn_exp2f(v);
        }
        int2 w;
        w.x = pack2(p[0], p[1]);
        w.y = pack2(p[2], p[3]);
        const int row = quad * 4 + r;
        // swizzled write: byte = row*128 + ((l16>>1)^(row&7))*16 + (l16&1)*8
        *(int2*)((char*)Psw + row * 128 + (((l16 >> 1) ^ (row & 7)) << 4) + ((l16 & 1) << 3)) = w;
    }

    // ---- P A-fragments (same-wave RAW through LDS, swizzled read)
    short8 pf[2];
    #pragma unroll
    for (int c = 0; c < 2; c++)
        pf[c] = *(const short8*)((const char*)Psw + l16 * 128 + ((((c << 2) | quad) ^ (l16 & 7)) << 4));

    // ---- row sums via MFMA (no rescale: accumulate directly)
    __builtin_amdgcn_s_setprio(1);
    floatx4 racc = {};
    racc = __builtin_amdgcn_mfma_f32_16x16x32_bf16(pf[0], ones, racc, 0, 0, 0);
    racc = __builtin_amdgcn_mfma_f32_16x16x32_bf16(pf[1], ones, racc, 0, 0, 0);

    #pragma unroll
    for (int r = 0; r < 4; r++)
        st.l[r] += racc[r];

    // ---- O += P V (swizzled, position-permuted both sides)
    #pragma unroll
    for (int d = 0; d < 4; d++) {
        #pragma unroll
        for (int c = 0; c < 2; c++) {
            const short8 vf = *(const short8*)&Vs[d * 16 + l16][((c * 4 + quad) ^ swz) * 8];
            st.o[d] = __builtin_amdgcn_mfma_f32_16x16x32_bf16(pf[c], vf, st.o[d], 0, 0, 0);
        }
    }
    __builtin_amdgcn_s_setprio(0);
}

__device__ __forceinline__ void stage_tile(
    const ushort_t* __restrict__ kg, const ushort_t* __restrict__ vg, int kb,
    ushort_t (*__restrict__ Ksb)[DH], ushort_t (*__restrict__ Vsb)[BKV],
    int wave, int l8r, int c8)
{
    #pragma unroll
    for (int i = wave; i < 8; i += 4) {
        const int row = i * 8 + l8r;
        const int cc  = (c8 ^ l8r) * 8;
        async_copy16(&kg[(size_t)(kb + row) * 2048 + cc], &Ksb[i * 8][0]);
        async_copy16(&vg[(size_t)row * S_LEN + kb + cc], &Vsb[i * 8][0]);
    }
}

__global__ __launch_bounds__(256, 4)
void attn_causal(const ushort_t* __restrict__ qk, const ushort_t* __restrict__ vt,
                 ushort_t* __restrict__ out)
{
    __shared__ ushort_t Ks[2][BKV][DH];       // double-buffered (16 KB)
    __shared__ ushort_t Vs[2][DH][BKV];       // double-buffered (16 KB)
    __shared__ ushort_t Ps[4][16][64];        // per-wave, XOR-swizzled (8 KB)
    // total 40960 B = 160 KB / 4 exactly

    const int tid  = threadIdx.x;
    const int lane = tid & 63;
    const int wave = tid >> 6;
    const int quad = lane >> 4;
    const int l16  = lane & 15;
    const int l8r  = lane >> 3;
    const int c8   = lane & 7;
    const int swz  = l16 & 7;

    // XCD-chunked swizzle: linear id (x-fastest) -> sid so that each XCD
    // (id%8) gets 128 consecutive sids = 8 full bh groups. K/V for those 8
    // heads = 8 x 512 KB = 4 MB = one XCD's L2.
    const int id  = blockIdx.y * 16 + blockIdx.x;
    const int sid = (id & 7) * 128 + (id >> 3);
    const int qa  = sid & 15;           // 0..15
    const int qb  = 31 - qa;            // 16..31
    const int bh  = sid >> 4;           // 0..63
    const int b   = bh >> 4;
    const int h   = bh & 15;

    const size_t qkbase = (size_t)b * S_LEN * 2048;
    const ushort_t* kg = qk + qkbase + D_MODEL + h * DH;
    const ushort_t* vg = vt + (size_t)(b * NH + h) * DH * S_LEN;

    TileState sa, sb;
    #pragma unroll
    for (int r = 0; r < 4; r++) { sa.l[r] = 0.f; sb.l[r] = 0.f; }
    #pragma unroll
    for (int d = 0; d < 4; d++) { sa.o[d] = (floatx4){}; sb.o[d] = (floatx4){}; }

    {
        const ushort_t* qpa = qk + qkbase + (size_t)(qa * 64 + wave * 16 + l16) * 2048 + h * DH;
        sa.qf[0] = *(const short8*)(qpa + quad * 8);
        sa.qf[1] = *(const short8*)(qpa + 32 + quad * 8);
        const ushort_t* qpb = qk + qkbase + (size_t)(qb * 64 + wave * 16 + l16) * 2048 + h * DH;
        sb.qf[0] = *(const short8*)(qpb + quad * 8);
        sb.qf[1] = *(const short8*)(qpb + 32 + quad * 8);
    }

    short8 ones;
    #pragma unroll
    for (int j = 0; j < 8; j++) ones[j] = (short)0x3F80;   // bf16 1.0

    // prologue: stage tile 0 into buffer 0
    stage_tile(kg, vg, 0, Ks[0], Vs[0], wave, l8r, c8);

    int cur = 0;
    for (int t = 0; t <= qb; t++) {
        // Drains this wave's DMA (vmcnt(0)) then barriers: buf[cur] is ready
        // and all waves are done reading buf[cur^1] from iteration t-1.
        __syncthreads();
        if (t < qb)
            stage_tile(kg, vg, (t + 1) * BKV, Ks[cur ^ 1], Vs[cur ^ 1], wave, l8r, c8);

        if (t <= qa) attn_tile(Ks[cur], Vs[cur], &Ps[wave][0][0], sa, t == qa, wave, quad, l16, swz, ones);
        attn_tile(Ks[cur], Vs[cur], &Ps[wave][0][0], sb, t == qb, wave, quad, l16, swz, ones);
        cur ^= 1;
    }

    // ---- epilogue: out[b, qi, h*64 + dh] = o / l  (both tiles)
    #pragma unroll
    for (int r = 0; r < 4; r++) {
        const float inva = 1.0f / sa.l[r];
        const float invb = 1.0f / sb.l[r];
        const int ra = qa * 64 + wave * 16 + quad * 4 + r;
        const int rb = qb * 64 + wave * 16 + quad * 4 + r;
        #pragma unroll
        for (int d = 0; d < 4; d++) {
            out[(size_t)(b * S_LEN + ra) * D_MODEL + h * DH + d * 16 + l16] = f2bf(sa.o[d][r] * inva);
            out[(size_t)(b * S_LEN + rb) * D_MODEL + h * DH + d * 16 + l16] = f2bf(sb.o[d][r] * invb);
        }
    }
}

// ---------------------------------------------------------------------------
extern "C" void kernel_launch(void* const* d_in, const int* in_sizes, int n_in,
                              void* d_out, int out_size, void* d_ws, size_t ws_size,
                              hipStream_t stream)
{
    const float* x    = (const float*)d_in[0];
    const float* Wqkv = (const float*)d_in[1];
    const float* bqkv = (const float*)d_in[2];
    const float* Wo   = (const float*)d_in[3];
    const float* bo   = (const float*)d_in[4];
    float* out = (float*)d_out;

    ushort_t* xb    = (ushort_t*)d_ws;                       // N0
    ushort_t* wqkvb = xb + N0;                               // N1
    ushort_t* wob   = wqkvb + N1;                            // N2
    ushort_t* qkbuf = wob + N2;                              // 8192*2048
    ushort_t* vtbuf = qkbuf + (size_t)M_ROWS * 2048;         // B*NH*DH*S
    ushort_t* att   = vtbuf + (size_t)BATCH * NH * DH * S_LEN; // 8192*1024
    // total = 92.3 MB

    cvt_f32_bf16<<<dim3((NQUADS + 255) / 256), dim3(256), 0, stream>>>(x, Wqkv, Wo, xb, wqkvb, wob);
    // QKV projection: M=8192, N=3072, K=1024. 256x128 tile, 8 waves, 144 KB
    // LDS, counted-vmcnt 3-slot pipeline, grid 24x32 = 768 = 3 rounds of 1/CU.
    gemm_pipe<false, true>
        <<<dim3((3 * D_MODEL) / 128, M_ROWS / 256), dim3(512), 0, stream>>>(
        xb, wqkvb, bqkv, qkbuf, vtbuf, M_ROWS, 3 * D_MODEL, D_MODEL);
    // causal attention (paired q-tiles, no-max softmax, dbuf K/V, XCD swizzle)
    attn_causal<<<dim3(16, BATCH * NH), dim3(256), 0, stream>>>(qkbuf, vtbuf, att);
    // output projection: M=8192, N=1024, K=1024. Same pipeline, grid 8x32 =
    // 256 = exactly 1 block/CU (fine for the pipeline: no cross-block need).
    gemm_pipe<true, false>
        <<<dim3(D_MODEL / 128, M_ROWS / 256), dim3(512), 0, stream>>>(
        att, wob, bo, out, nullptr, M_ROWS, D_MODEL, D_MODEL);
}

// Round 7
// 257.805 us; speedup vs baseline: 2.5333x; 1.0443x over previous
//
#include <hip/hip_runtime.h>

#define D_MODEL 1024
#define S_LEN   2048
#define BATCH   4
#define NH      16
#define DH      64
#define M_ROWS  (BATCH * S_LEN)   // 8192

typedef __attribute__((ext_vector_type(8))) short short8;
typedef __attribute__((ext_vector_type(4))) float floatx4;
typedef unsigned short ushort_t;
typedef __attribute__((ext_vector_type(4))) ushort_t ushortx4;

__device__ __forceinline__ ushort_t f2bf(float f) {
    union { float f; unsigned u; } v; v.f = f;
    unsigned r = v.u + 0x7FFFu + ((v.u >> 16) & 1u);
    return (ushort_t)(r >> 16);
}

// pack two f32 -> two bf16 (truncating) in one v_perm: low = lo, high = hi
__device__ __forceinline__ int pack2(float lo, float hi) {
    return (int)__builtin_amdgcn_perm(__float_as_uint(hi), __float_as_uint(lo), 0x07060302u);
}

// async global->LDS, 16B/lane; LDS dest = wave-uniform base + lane*16
__device__ __forceinline__ void async_copy16(const ushort_t* g, ushort_t* l) {
    __builtin_amdgcn_global_load_lds(
        (const __attribute__((address_space(1))) void*)g,
        (__attribute__((address_space(3))) void*)l,
        16, 0, 0);
}

// ---------------------------------------------------------------------------
// fp32 -> bf16 downcast of x, W_qkv, W_o into workspace. 4 elems / thread.
// ---------------------------------------------------------------------------
#define N0 (M_ROWS * D_MODEL)        // x:      8,388,608
#define N1 (3 * D_MODEL * D_MODEL)   // W_qkv:  3,145,728
#define N2 (D_MODEL * D_MODEL)       // W_o:    1,048,576
#define NQUADS ((N0 + N1 + N2) / 4)

__global__ __launch_bounds__(256)
void cvt_f32_bf16(const float* __restrict__ s0, const float* __restrict__ s1,
                  const float* __restrict__ s2, ushort_t* __restrict__ d0,
                  ushort_t* __restrict__ d1, ushort_t* __restrict__ d2)
{
    const int q = blockIdx.x * 256 + threadIdx.x;
    if (q >= NQUADS) return;
    const float* s; ushort_t* d; int e;
    if (q < N0 / 4)            { s = s0; d = d0; e = q * 4; }
    else if (q < (N0 + N1) / 4){ s = s1; d = d1; e = q * 4 - N0; }
    else                       { s = s2; d = d2; e = q * 4 - N0 - N1; }
    const float4 v = *(const float4*)&s[e];
    ushortx4 o;
    o[0] = f2bf(v.x); o[1] = f2bf(v.y); o[2] = f2bf(v.z); o[3] = f2bf(v.w);
    *(ushortx4*)&d[e] = o;
}

// ---------------------------------------------------------------------------
// NT GEMM: C[M,N] = A[M,K]*B[N,K]^T + bias[N]. bf16 in, fp32 acc.
// 128x128 tile, BK=64, 8 WAVES of 64x32 each (2M x 4N wave grid).
// Two-barrier K-step (stage -> sync -> compute -> sync): cross-block overlap
// hides DMA. The 64x32 wave tile keeps acc at 32 f32 (vs 64/128 in earlier
// rounds) -> ~80-90 total regs/wave -> ~24 waves/CU = 3 resident blocks
// (LDS 32 KB allows 5). Staging-throughput model from rounds 1/4/5 + m97:
// aggregate global_load_lds rate scales with resident blocks (7.6 TB/s @4,
// 6.3 @2, 5 @1; m97 13.2 @3) -> more residency = faster staging = less
// exposed latency. NO tight VGPR cap (round-3 spill lesson): MINW=4.
// XCD-aware bijective block swizzle (shared A-panels within an XCD's L2).
// XOR-swizzled unpadded LDS tiles: LDS(row,chunk) = global chunk^(row&7).
// VSPLIT (QKV): cols [0,2048) -> qk; cols [2048,3072) -> vt[b][h][dh][sperm],
// sperm = per-64-tile pos(k)=(k&15)*4+(k>>4) (matches attention fragments).
// Q columns (col < D_MODEL) pre-scaled by C2 = 0.125*log2(e) (exp2-domain).
// ---------------------------------------------------------------------------
template<bool F32OUT, bool VSPLIT>
__global__ __launch_bounds__(512, 4)
void gemm_bt(const ushort_t* __restrict__ A, const ushort_t* __restrict__ B,
             const float* __restrict__ bias, void* __restrict__ Cv,
             ushort_t* __restrict__ vt, int M, int N, int K)
{
    constexpr int BK = 64;
    constexpr float C2 = 0.18033688011112042f;   // 0.125 * log2(e)
    __shared__ ushort_t As[128][BK];
    __shared__ ushort_t Bs[128][BK];

    const int tid  = threadIdx.x;
    const int lane = tid & 63;
    const int wave = tid >> 6;           // 0..7
    const int quad = lane >> 4;
    const int l16  = lane & 15;
    const int l8r  = lane >> 3;
    const int c8   = lane & 7;
    const int swz  = l16 & 7;

    // XCD-aware bijective swizzle (grid % 8 == 0 for both instantiations).
    const int gdx = gridDim.x;
    const int bid = blockIdx.y * gdx + blockIdx.x;
    const int nwg = gdx * gridDim.y;
    const int sw  = (bid & 7) * (nwg >> 3) + (bid >> 3);
    const int bm  = (sw / gdx) * 128;
    const int bn  = (sw % gdx) * 128;

    const int wm = (wave & 1) * 64;      // 2 wave-rows of 64
    const int wn = (wave >> 1) * 32;     // 4 wave-cols of 32

    floatx4 acc[4][2] = {};

    for (int k0 = 0; k0 < K; k0 += BK) {
        __syncthreads();            // all waves done reading previous tile
        #pragma unroll
        for (int i = wave; i < 16; i += 8) {
            const int row = i * 8 + l8r;
            const int cc  = (c8 ^ l8r) * 8;
            async_copy16(&A[(size_t)(bm + row) * K + k0 + cc], &As[i * 8][0]);
            async_copy16(&B[(size_t)(bn + row) * K + k0 + cc], &Bs[i * 8][0]);
        }
        __syncthreads();            // drains vmcnt(0): tile ready

        #pragma unroll
        for (int h = 0; h < 2; h++) {
            short8 af[4], bfr[2];
            #pragma unroll
            for (int i = 0; i < 4; i++)
                af[i]  = *(const short8*)&As[wm + i * 16 + l16][((h * 4 + quad) ^ swz) * 8];
            #pragma unroll
            for (int i = 0; i < 2; i++)
                bfr[i] = *(const short8*)&Bs[wn + i * 16 + l16][((h * 4 + quad) ^ swz) * 8];

            #pragma unroll
            for (int mi = 0; mi < 4; mi++)
                #pragma unroll
                for (int ni = 0; ni < 2; ni++)
                    acc[mi][ni] = __builtin_amdgcn_mfma_f32_16x16x32_bf16(af[mi], bfr[ni], acc[mi][ni], 0, 0, 0);
        }
    }

    #pragma unroll
    for (int ni = 0; ni < 2; ni++) {
        const int col = bn + wn + ni * 16 + l16;
        const float bv = bias[col];
        #pragma unroll
        for (int mi = 0; mi < 4; mi++)
            #pragma unroll
            for (int r = 0; r < 4; r++) {
                const int row = bm + wm + mi * 16 + quad * 4 + r;
                const float val = acc[mi][ni][r] + bv;
                if (VSPLIT) {
                    if (col < 2 * D_MODEL) {
                        // Q columns carry the softmax scale; K columns unscaled
                        const float vv = (col < D_MODEL) ? val * C2 : val;
                        ((ushort_t*)Cv)[(size_t)row * 2048 + col] = f2bf(vv);
                    } else {
                        const int vcol = col - 2 * D_MODEL;
                        const int h = vcol >> 6, dh = vcol & 63;
                        const int b = row >> 11, s2 = row & 2047;
                        const int sp = (s2 & ~63) | ((s2 & 15) << 2) | ((s2 >> 4) & 3);
                        vt[(((size_t)(b * NH + h)) * DH + dh) * S_LEN + sp] = f2bf(val);
                    }
                } else if (F32OUT) {
                    ((float*)Cv)[(size_t)row * N + col] = val;
                } else {
                    ((ushort_t*)Cv)[(size_t)row * N + col] = f2bf(val);
                }
            }
    }
}

// ---------------------------------------------------------------------------
// Causal flash attention: UNIFORM-WORK PAIRING, NO-MAX softmax, DOUBLE-
// BUFFERED K/V staging, XCD-chunked swizzle, setprio MFMA clusters.
// (Unchanged from round 5.)
// ---------------------------------------------------------------------------
#define BKV 64

struct TileState {
    short8  qf[2];
    floatx4 o[4];
    float   l[4];
};

__device__ __forceinline__ void attn_tile(
    const ushort_t (*__restrict__ Ks)[DH], const ushort_t (*__restrict__ Vs)[BKV],
    ushort_t* __restrict__ Psw, TileState& st, bool diag,
    int wave, int quad, int l16, int swz, short8 ones)
{
    // ---- S = Q K^T (swizzled, conflict-free); Q pre-scaled by 0.125*log2e
    floatx4 sc[4];
    __builtin_amdgcn_s_setprio(1);
    #pragma unroll
    for (int ns = 0; ns < 4; ns++) {
        const short8 kf0 = *(const short8*)&Ks[ns * 16 + l16][(quad ^ swz) * 8];
        const short8 kf1 = *(const short8*)&Ks[ns * 16 + l16][((4 + quad) ^ swz) * 8];
        floatx4 z = {};
        z = __builtin_amdgcn_mfma_f32_16x16x32_bf16(st.qf[0], kf0, z, 0, 0, 0);
        z = __builtin_amdgcn_mfma_f32_16x16x32_bf16(st.qf[1], kf1, z, 0, 0, 0);
        sc[ns] = z;
    }
    __builtin_amdgcn_s_setprio(0);

    // ---- causal mask (diag only) + exp2 + pack + one b64 write per row
    #pragma unroll
    for (int r = 0; r < 4; r++) {
        const int qloc = wave * 16 + quad * 4 + r;   // row within the 64-row q-tile
        float p[4];
        #pragma unroll
        for (int ns = 0; ns < 4; ns++) {
            float v = sc[ns][r];
            if (diag) {
                const int kj = ns * 16 + l16;
                v = (kj <= qloc) ? v : -1e30f;
            }
            p[ns] = __builtin_amdgcn_exp2f(v);
        }
        int2 w;
        w.x = pack2(p[0], p[1]);
        w.y = pack2(p[2], p[3]);
        const int row = quad * 4 + r;
        // swizzled write: byte = row*128 + ((l16>>1)^(row&7))*16 + (l16&1)*8
        *(int2*)((char*)Psw + row * 128 + (((l16 >> 1) ^ (row & 7)) << 4) + ((l16 & 1) << 3)) = w;
    }

    // ---- P A-fragments (same-wave RAW through LDS, swizzled read)
    short8 pf[2];
    #pragma unroll
    for (int c = 0; c < 2; c++)
        pf[c] = *(const short8*)((const char*)Psw + l16 * 128 + ((((c << 2) | quad) ^ (l16 & 7)) << 4));

    // ---- row sums via MFMA (no rescale: accumulate directly)
    __builtin_amdgcn_s_setprio(1);
    floatx4 racc = {};
    racc = __builtin_amdgcn_mfma_f32_16x16x32_bf16(pf[0], ones, racc, 0, 0, 0);
    racc = __builtin_amdgcn_mfma_f32_16x16x32_bf16(pf[1], ones, racc, 0, 0, 0);

    #pragma unroll
    for (int r = 0; r < 4; r++)
        st.l[r] += racc[r];

    // ---- O += P V (swizzled, position-permuted both sides)
    #pragma unroll
    for (int d = 0; d < 4; d++) {
        #pragma unroll
        for (int c = 0; c < 2; c++) {
            const short8 vf = *(const short8*)&Vs[d * 16 + l16][((c * 4 + quad) ^ swz) * 8];
            st.o[d] = __builtin_amdgcn_mfma_f32_16x16x32_bf16(pf[c], vf, st.o[d], 0, 0, 0);
        }
    }
    __builtin_amdgcn_s_setprio(0);
}

__device__ __forceinline__ void stage_tile(
    const ushort_t* __restrict__ kg, const ushort_t* __restrict__ vg, int kb,
    ushort_t (*__restrict__ Ksb)[DH], ushort_t (*__restrict__ Vsb)[BKV],
    int wave, int l8r, int c8)
{
    #pragma unroll
    for (int i = wave; i < 8; i += 4) {
        const int row = i * 8 + l8r;
        const int cc  = (c8 ^ l8r) * 8;
        async_copy16(&kg[(size_t)(kb + row) * 2048 + cc], &Ksb[i * 8][0]);
        async_copy16(&vg[(size_t)row * S_LEN + kb + cc], &Vsb[i * 8][0]);
    }
}

__global__ __launch_bounds__(256, 4)
void attn_causal(const ushort_t* __restrict__ qk, const ushort_t* __restrict__ vt,
                 ushort_t* __restrict__ out)
{
    __shared__ ushort_t Ks[2][BKV][DH];       // double-buffered (16 KB)
    __shared__ ushort_t Vs[2][DH][BKV];       // double-buffered (16 KB)
    __shared__ ushort_t Ps[4][16][64];        // per-wave, XOR-swizzled (8 KB)
    // total 40960 B = 160 KB / 4 exactly

    const int tid  = threadIdx.x;
    const int lane = tid & 63;
    const int wave = tid >> 6;
    const int quad = lane >> 4;
    const int l16  = lane & 15;
    const int l8r  = lane >> 3;
    const int c8   = lane & 7;
    const int swz  = l16 & 7;

    // XCD-chunked swizzle: each XCD (id%8) gets 128 consecutive sids = 8 full
    // bh groups -> K/V for those 8 heads = 4 MB = one XCD's L2.
    const int id  = blockIdx.y * 16 + blockIdx.x;
    const int sid = (id & 7) * 128 + (id >> 3);
    const int qa  = sid & 15;           // 0..15
    const int qb  = 31 - qa;            // 16..31
    const int bh  = sid >> 4;           // 0..63
    const int b   = bh >> 4;
    const int h   = bh & 15;

    const size_t qkbase = (size_t)b * S_LEN * 2048;
    const ushort_t* kg = qk + qkbase + D_MODEL + h * DH;
    const ushort_t* vg = vt + (size_t)(b * NH + h) * DH * S_LEN;

    TileState sa, sb;
    #pragma unroll
    for (int r = 0; r < 4; r++) { sa.l[r] = 0.f; sb.l[r] = 0.f; }
    #pragma unroll
    for (int d = 0; d < 4; d++) { sa.o[d] = (floatx4){}; sb.o[d] = (floatx4){}; }

    {
        const ushort_t* qpa = qk + qkbase + (size_t)(qa * 64 + wave * 16 + l16) * 2048 + h * DH;
        sa.qf[0] = *(const short8*)(qpa + quad * 8);
        sa.qf[1] = *(const short8*)(qpa + 32 + quad * 8);
        const ushort_t* qpb = qk + qkbase + (size_t)(qb * 64 + wave * 16 + l16) * 2048 + h * DH;
        sb.qf[0] = *(const short8*)(qpb + quad * 8);
        sb.qf[1] = *(const short8*)(qpb + 32 + quad * 8);
    }

    short8 ones;
    #pragma unroll
    for (int j = 0; j < 8; j++) ones[j] = (short)0x3F80;   // bf16 1.0

    // prologue: stage tile 0 into buffer 0
    stage_tile(kg, vg, 0, Ks[0], Vs[0], wave, l8r, c8);

    int cur = 0;
    for (int t = 0; t <= qb; t++) {
        // Drains this wave's DMA (vmcnt(0)) then barriers: buf[cur] is ready
        // and all waves are done reading buf[cur^1] from iteration t-1.
        __syncthreads();
        if (t < qb)
            stage_tile(kg, vg, (t + 1) * BKV, Ks[cur ^ 1], Vs[cur ^ 1], wave, l8r, c8);

        if (t <= qa) attn_tile(Ks[cur], Vs[cur], &Ps[wave][0][0], sa, t == qa, wave, quad, l16, swz, ones);
        attn_tile(Ks[cur], Vs[cur], &Ps[wave][0][0], sb, t == qb, wave, quad, l16, swz, ones);
        cur ^= 1;
    }

    // ---- epilogue: out[b, qi, h*64 + dh] = o / l  (both tiles)
    #pragma unroll
    for (int r = 0; r < 4; r++) {
        const float inva = 1.0f / sa.l[r];
        const float invb = 1.0f / sb.l[r];
        const int ra = qa * 64 + wave * 16 + quad * 4 + r;
        const int rb = qb * 64 + wave * 16 + quad * 4 + r;
        #pragma unroll
        for (int d = 0; d < 4; d++) {
            out[(size_t)(b * S_LEN + ra) * D_MODEL + h * DH + d * 16 + l16] = f2bf(sa.o[d][r] * inva);
            out[(size_t)(b * S_LEN + rb) * D_MODEL + h * DH + d * 16 + l16] = f2bf(sb.o[d][r] * invb);
        }
    }
}

// ---------------------------------------------------------------------------
extern "C" void kernel_launch(void* const* d_in, const int* in_sizes, int n_in,
                              void* d_out, int out_size, void* d_ws, size_t ws_size,
                              hipStream_t stream)
{
    const float* x    = (const float*)d_in[0];
    const float* Wqkv = (const float*)d_in[1];
    const float* bqkv = (const float*)d_in[2];
    const float* Wo   = (const float*)d_in[3];
    const float* bo   = (const float*)d_in[4];
    float* out = (float*)d_out;

    ushort_t* xb    = (ushort_t*)d_ws;                       // N0
    ushort_t* wqkvb = xb + N0;                               // N1
    ushort_t* wob   = wqkvb + N1;                            // N2
    ushort_t* qkbuf = wob + N2;                              // 8192*2048
    ushort_t* vtbuf = qkbuf + (size_t)M_ROWS * 2048;         // B*NH*DH*S
    ushort_t* att   = vtbuf + (size_t)BATCH * NH * DH * S_LEN; // 8192*1024
    // total = 92.3 MB

    cvt_f32_bf16<<<dim3((NQUADS + 255) / 256), dim3(256), 0, stream>>>(x, Wqkv, Wo, xb, wqkvb, wob);
    // QKV projection: M=8192, N=3072, K=1024. 128x128 tile, 8 waves of
    // 64x32, 32 KB LDS, ~3 resident blocks/CU. Grid 24x64 = 1536.
    gemm_bt<false, true>
        <<<dim3((3 * D_MODEL) / 128, M_ROWS / 128), dim3(512), 0, stream>>>(
        xb, wqkvb, bqkv, qkbuf, vtbuf, M_ROWS, 3 * D_MODEL, D_MODEL);
    // causal attention (paired q-tiles, no-max softmax, dbuf K/V, XCD swizzle)
    attn_causal<<<dim3(16, BATCH * NH), dim3(256), 0, stream>>>(qkbuf, vtbuf, att);
    // output projection: M=8192, N=1024, K=1024. Same kernel, grid 8x64=512.
    gemm_bt<true, false>
        <<<dim3(D_MODEL / 128, M_ROWS / 128), dim3(512), 0, stream>>>(
        att, wob, bo, out, nullptr, M_ROWS, D_MODEL, D_MODEL);
}